// Round 7
// baseline (1592.726 us; speedup 1.0000x reference)
//
#include <hip/hip_runtime.h>
#include <math.h>

#define TT 1024
#define NB 64

typedef float f32x4 __attribute__((ext_vector_type(4)));
typedef __bf16 bf16x8 __attribute__((ext_vector_type(8)));

__device__ __forceinline__ float4 ld4(const float* p){ return *(const float4*)p; }
__device__ __forceinline__ unsigned short bf16rne(float x){
  unsigned u = __float_as_uint(x);
  return (unsigned short)((u + 0x7FFF + ((u >> 16) & 1)) >> 16);
}

// ================= bf16 MFMA GEMM: C = epi(A @ B^T_panels) =================
template<int EPI, int OUTBF>
__global__ __launch_bounds__(256)
void mgemm_k(const unsigned short* __restrict__ A, const unsigned short* __restrict__ B,
             void* __restrict__ Cv, int K, int lda, int ldb, int ldc,
             long sA, long sB, long sC,
             const float* __restrict__ bias,
             const float* __restrict__ e1, long sE1, const float* __restrict__ e2)
{
  const int bz = blockIdx.z;
  A += (long)bz * sA; B += (long)bz * sB;
  __shared__ char lds[16384];
  char* As = lds; char* Bs = lds + 8192;
  const int tid = threadIdx.x;
  const int l = tid & 63, wid = tid >> 6;
  const int wr = wid >> 1, wc = wid & 1;
  const int m0 = blockIdx.y * 128, n0 = blockIdx.x * 128;
  const int lrow = l & 15, lslot = (l >> 4) << 4;
  f32x4 acc[4][4] = {};

  for (int kk = 0; kk < K; kk += 32) {
#pragma unroll
    for (int i = 0; i < 2; ++i) {
      int idx = i * 256 + tid;
      int row = idx >> 2, c16 = (idx & 3) << 4;
      int sw = c16 ^ (((row >> 1) & 3) << 4);
      uint4 va = *(const uint4*)(A + (long)(m0 + row) * lda + kk + (c16 >> 1));
      *(uint4*)(As + row * 64 + sw) = va;
      uint4 vb = *(const uint4*)(B + (long)(n0 + row) * ldb + kk + (c16 >> 1));
      *(uint4*)(Bs + row * 64 + sw) = vb;
    }
    __syncthreads();
    bf16x8 af[4], bfr[4];
#pragma unroll
    for (int t = 0; t < 4; ++t) {
      int ra = wr * 64 + t * 16 + lrow;
      af[t]  = *(const bf16x8*)(As + ra * 64 + (lslot ^ (((ra >> 1) & 3) << 4)));
      int rb = wc * 64 + t * 16 + lrow;
      bfr[t] = *(const bf16x8*)(Bs + rb * 64 + (lslot ^ (((rb >> 1) & 3) << 4)));
    }
#pragma unroll
    for (int mi = 0; mi < 4; ++mi)
#pragma unroll
      for (int ni = 0; ni < 4; ++ni)
        acc[mi][ni] = __builtin_amdgcn_mfma_f32_16x16x32_bf16(af[mi], bfr[ni], acc[mi][ni], 0, 0, 0);
    __syncthreads();
  }

  float* Cf = (float*)Cv; unsigned short* Cb = (unsigned short*)Cv;
  if (OUTBF) Cb += (long)bz * sC; else Cf += (long)bz * sC;
  if (e1) e1 += (long)bz * sE1;
#pragma unroll
  for (int mi = 0; mi < 4; ++mi)
#pragma unroll
  for (int ni = 0; ni < 4; ++ni)
#pragma unroll
  for (int r = 0; r < 4; ++r) {
    int m = m0 + wr * 64 + mi * 16 + ((l >> 4) << 2) + r;
    int n = n0 + wc * 64 + ni * 16 + (l & 15);
    float v = acc[mi][ni][r];
    if (EPI == 1) v = tanhf(v + bias[n]);
    else if (EPI == 2) v = (m == n) ? 0.f : expf(tanhf(v));
    else if (EPI == 3) v = fmaxf(v + bias[n], 0.f);
    else if (EPI == 4) v = v + e1[m] * e2[n];
    if (OUTBF) Cb[(long)m * ldc + n] = bf16rne(v);
    else       Cf[(long)m * ldc + n] = v;
  }
}

// ---------------- feature split ----------------
__global__ void split_k(const float* __restrict__ in, float* __restrict__ sem, float* __restrict__ str){
  long row = blockIdx.x;
  int c = threadIdx.x << 2;
  float4 v = ld4(in + row * 1024 + c);
  float* dst;
  if (c < 256)      dst = sem + row * 512 + c;
  else if (c < 512) dst = str + row * 512 + (c - 256);
  else if (c < 768) dst = sem + row * 512 + 256 + (c - 512);
  else              dst = str + row * 512 + 256 + (c - 768);
  *(float4*)dst = v;
}

// ---------------- casts ----------------
__global__ void castrow_k(const float* __restrict__ src, unsigned short* __restrict__ dst){
  long i = ((long)blockIdx.x * 256 + threadIdx.x) << 2;
  float4 v = ld4(src + i);
  unsigned lo = bf16rne(v.x) | ((unsigned)bf16rne(v.y) << 16);
  unsigned hi = bf16rne(v.z) | ((unsigned)bf16rne(v.w) << 16);
  uint2 w; w.x = lo; w.y = hi;
  *(uint2*)(dst + i) = w;
}

__global__ __launch_bounds__(256) void castT_k(const float* __restrict__ src, unsigned short* __restrict__ dst,
                                               int R, int C, long sS, long sD){
  int b = blockIdx.z;
  src += (long)b * sS; dst += (long)b * sD;
  __shared__ float t[32][33];
  int r0 = blockIdx.y * 32, c0 = blockIdx.x * 32;
  int tx = threadIdx.x & 31, ty = threadIdx.x >> 5;
#pragma unroll
  for (int j = 0; j < 32; j += 8)
    t[ty + j][tx] = src[(long)(r0 + ty + j) * C + c0 + tx];
  __syncthreads();
#pragma unroll
  for (int j = 0; j < 32; j += 8)
    dst[(long)(c0 + ty + j) * R + r0 + tx] = bf16rne(t[tx][ty + j]);
}

__global__ void semcopy_k(const float* __restrict__ sem, unsigned short* __restrict__ finpb){
  long idx = ((long)blockIdx.x * 256 + threadIdx.x) << 2;
  long row = idx >> 9; int col = (int)(idx & 511);
  float4 v = ld4(sem + idx);
  unsigned lo = bf16rne(v.x) | ((unsigned)bf16rne(v.y) << 16);
  unsigned hi = bf16rne(v.z) | ((unsigned)bf16rne(v.w) << 16);
  uint2 w; w.x = lo; w.y = hi;
  *(uint2*)(finpb + row * 1536 + col) = w;
}

// ---------------- f_i = exp(tanh(str . wfi)) ----------------
__global__ void fi_k(const float* __restrict__ str, const float* __restrict__ wfi, float* __restrict__ fi){
  int row = blockIdx.x * 4 + (threadIdx.x >> 6);
  int lane = threadIdx.x & 63;
  const float* p = str + (long)row * 512;
  float acc = 0.f;
  for (int c = lane; c < 512; c += 64) acc = fmaf(p[c], wfi[c], acc);
  for (int off = 32; off; off >>= 1) acc += __shfl_down(acc, off, 64);
  if (lane == 0) fi[row] = expf(tanhf(acc));
}

// ---------------- column sums (8 row-chunk partials) ----------------
__global__ void colsum_k(const float* __restrict__ A, float* __restrict__ csp){
  int b = blockIdx.y, rc = blockIdx.z;
  int j = blockIdx.x * 256 + threadIdx.x;
  const float* p = A + (long)b * TT * TT + (long)rc * 128 * TT + j;
  float acc = 0.f;
  for (int i = 0; i < 128; ++i) acc += p[(long)i * TT];
  csp[rc * 8192 + b * TT + j] = acc;
}

// ---------------- build L_bar (+ emit Cold0 hi/lo = split(W[:, 0:64])) ----------------
__global__ void buildw_k(const float* __restrict__ A, const float* __restrict__ fi,
                         const float* __restrict__ csp, float* __restrict__ W,
                         unsigned short* __restrict__ Ch0, unsigned short* __restrict__ Cl0){
  long idx = (long)blockIdx.x * 256 + threadIdx.x;
  long b = idx >> 20;
  long r = idx & 1048575;
  int i = (int)(r >> 10), j = (int)(r & 1023);
  float v;
  if (i == 0)      v = fi[b * TT + j];
  else if (i == j) {
    v = 0.f;
#pragma unroll
    for (int c = 0; c < 8; ++c) v += csp[c * 8192 + b * TT + j];
  }
  else             v = -A[idx];
  W[idx] = v;
  if (j < 64) {
    unsigned short h = bf16rne(v);
    float hf = __uint_as_float((unsigned)h << 16);
    Ch0[b * 65536 + i * 64 + j] = h;
    Cl0[b * 65536 + i * 64 + j] = bf16rne(v - hf);
  }
}

// ---------------- GJ: 64x64 diag-block inverse, ping-pong LDS, 1 barrier/step ----------------
__global__ __launch_bounds__(256, 1) void gj_dinv_k(const float* __restrict__ W, float* __restrict__ Dinv, int k0){
  __shared__ float Pa[64][68];
  __shared__ float Pb[64][68];
  int b = blockIdx.x;
  int tid = threadIdx.x;
  int r = tid & 63, q16 = (tid >> 6) << 4;
  const float* Wb = W + (long)b * TT * TT + (long)(k0 + r) * TT + k0 + q16;
#pragma unroll
  for (int j = 0; j < 16; j += 4) *(float4*)&Pa[r][q16 + j] = ld4(Wb + j);
  __syncthreads();
#define DSTEP(kv, SRC, DST) { \
    int k_ = (kv); \
    float pk = SRC[k_][k_]; \
    float f  = SRC[r][k_]; \
    float pr = 1.f / pk; \
    bool piv = (r == k_); \
    float t = piv ? -pr : f * pr; \
    float ov[16]; \
    _Pragma("unroll") \
    for (int c = 0; c < 16; ++c) { \
      float pv = SRC[k_][q16 + c]; \
      float z = piv ? 0.f : SRC[r][q16 + c]; \
      float val = fmaf(-t, pv, z); \
      if (q16 + c == k_) val = -t; \
      ov[c] = val; \
    } \
    _Pragma("unroll") \
    for (int j = 0; j < 16; j += 4) *(float4*)&DST[r][q16 + j] = *(float4*)&ov[j]; \
    __syncthreads(); }
  for (int k = 0; k < 64; k += 2) {
    DSTEP(k, Pa, Pb)
    DSTEP(k + 1, Pb, Pa)
  }
  float* Db = Dinv + b * 4096 + r * 64 + q16;
#pragma unroll
  for (int j = 0; j < 16; j += 4) *(float4*)(Db + j) = *(float4*)&Pa[r][q16 + j];
}

// ---------------- GJ: Rnew = Dinv @ W[K,:] (cols K := Dinv); emit fp32 + R^T hi/lo bf16 ----------------
__global__ __launch_bounds__(256) void gj_prep_k(const float* __restrict__ W, const float* __restrict__ Dinv,
                                                 float* __restrict__ Rnew,
                                                 unsigned short* __restrict__ RTh, unsigned short* __restrict__ RTl,
                                                 int k0){
  int b = blockIdx.y;
  int p = blockIdx.x;                    // 0..63
  int j4 = threadIdx.x << 2;             // 0..1020
  const float* Wb = W + (long)b * TT * TT + (long)k0 * TT + j4;
  const float* Db = Dinv + b * 4096 + p * 64;
  float4 acc = {0.f, 0.f, 0.f, 0.f};
  for (int qq = 0; qq < 64; ++qq) {
    float d = Db[qq];
    float4 w = ld4(Wb + (long)qq * TT);
    acc.x = fmaf(d, w.x, acc.x); acc.y = fmaf(d, w.y, acc.y);
    acc.z = fmaf(d, w.z, acc.z); acc.w = fmaf(d, w.w, acc.w);
  }
  if (j4 >= k0 && j4 < k0 + NB) acc = ld4(Db + (j4 - k0));
  *(float4*)(Rnew + (long)b * 65536 + p * 1024 + j4) = acc;
  unsigned short* th = RTh + (long)b * 65536 + (long)j4 * 64 + p;
  unsigned short* tl = RTl + (long)b * 65536 + (long)j4 * 64 + p;
  float vs[4] = {acc.x, acc.y, acc.z, acc.w};
#pragma unroll
  for (int e = 0; e < 4; ++e) {
    unsigned short h = bf16rne(vs[e]);
    float hf = __uint_as_float((unsigned)h << 16);
    th[e * 64] = h;
    tl[e * 64] = bf16rne(vs[e] - hf);
  }
}

// ---------------- GJ trailing update via bf16x3 split MFMA ----------------
// W = (colK?0:W) - C@R; rowK rows := Rnew(fp32); side-write next Cold panel hi/lo.
__global__ __launch_bounds__(256) void gupd_k(const unsigned short* __restrict__ Ch, const unsigned short* __restrict__ Cl,
                                              const unsigned short* __restrict__ RTh, const unsigned short* __restrict__ RTl,
                                              const float* __restrict__ Rnew, float* __restrict__ W,
                                              unsigned short* __restrict__ ChN, unsigned short* __restrict__ ClN, int k0){
  int b = blockIdx.z;
  const unsigned short* Ahp = Ch + (long)b * 65536;
  const unsigned short* Alp = Cl + (long)b * 65536;
  const unsigned short* Bhp = RTh + (long)b * 65536;
  const unsigned short* Blp = RTl + (long)b * 65536;
  const float* Rb = Rnew + (long)b * 65536;
  float* Wb = W + (long)b * 1048576;
  unsigned short* CnH = ChN + (long)b * 65536;
  unsigned short* CnL = ClN + (long)b * 65536;
  const int tid = threadIdx.x, l = tid & 63, wid = tid >> 6;
  const int wr = wid >> 1, wc = wid & 1;
  const int m0 = blockIdx.y * 128, n0 = blockIdx.x * 128;
  const int lrow = l & 15, kc = (l >> 4) << 3;
  f32x4 acc[4][4] = {};
#pragma unroll
  for (int kk = 0; kk < 64; kk += 32) {
    bf16x8 ah[4], al[4], bh[4], bl[4];
#pragma unroll
    for (int t = 0; t < 4; ++t) {
      int ra = m0 + wr * 64 + t * 16 + lrow;
      ah[t] = *(const bf16x8*)(Ahp + (long)ra * 64 + kk + kc);
      al[t] = *(const bf16x8*)(Alp + (long)ra * 64 + kk + kc);
      int rb = n0 + wc * 64 + t * 16 + lrow;
      bh[t] = *(const bf16x8*)(Bhp + (long)rb * 64 + kk + kc);
      bl[t] = *(const bf16x8*)(Blp + (long)rb * 64 + kk + kc);
    }
#pragma unroll
    for (int mi = 0; mi < 4; ++mi)
#pragma unroll
      for (int ni = 0; ni < 4; ++ni) {
        acc[mi][ni] = __builtin_amdgcn_mfma_f32_16x16x32_bf16(ah[mi], bh[ni], acc[mi][ni], 0, 0, 0);
        acc[mi][ni] = __builtin_amdgcn_mfma_f32_16x16x32_bf16(ah[mi], bl[ni], acc[mi][ni], 0, 0, 0);
        acc[mi][ni] = __builtin_amdgcn_mfma_f32_16x16x32_bf16(al[mi], bh[ni], acc[mi][ni], 0, 0, 0);
      }
  }
#pragma unroll
  for (int mi = 0; mi < 4; ++mi)
#pragma unroll
  for (int ni = 0; ni < 4; ++ni)
#pragma unroll
  for (int r = 0; r < 4; ++r) {
    int m = m0 + wr * 64 + mi * 16 + ((l >> 4) << 2) + r;
    int n = n0 + wc * 64 + ni * 16 + (l & 15);
    bool rowK = (m >= k0 && m < k0 + 64);
    bool colK = (n >= k0 && n < k0 + 64);
    float v;
    if (rowK)      v = Rb[(long)(m - k0) * 1024 + n];
    else if (colK) v = -acc[mi][ni][r];
    else           v = Wb[(long)m * 1024 + n] - acc[mi][ni][r];
    Wb[(long)m * 1024 + n] = v;
    int cn = n - k0 - 64;
    if (cn >= 0 && cn < 64) {
      unsigned short h = bf16rne(v);
      float hf = __uint_as_float((unsigned)h << 16);
      CnH[(long)m * 64 + cn] = h;
      CnL[(long)m * 64 + cn] = bf16rne(v - hf);
    }
  }
}

// ---------------- d0, diag, df col 0 ----------------
__global__ void ddiag_k(const float* __restrict__ W, const float* __restrict__ fi,
                        float* __restrict__ d0, float* __restrict__ diag, float* __restrict__ dfout){
  int t = blockIdx.x * 256 + threadIdx.x;
  int b = t >> 10, i = t & 1023;
  const float* Wb = W + (long)b * TT * TT;
  float dv = fi[t] * Wb[(long)i * TT];
  d0[t] = dv;
  diag[t] = Wb[(long)i * TT + i];
  dfout[(long)b * TT * 1025 + (long)i * 1025] = dv;
}

// ---------------- dx: compute, emit bf16 dx + bf16 dx^T + df store ----------------
__global__ __launch_bounds__(256) void dx_k(const float* __restrict__ A, const float* __restrict__ W,
                                            const float* __restrict__ diag, float* __restrict__ dfout,
                                            unsigned short* __restrict__ dxb, unsigned short* __restrict__ dxTb){
  int b = blockIdx.z;
  int i0 = blockIdx.y * 64, j0 = blockIdx.x * 64;
  const float* Wb = W + (long)b * TT * TT;
  const float* Ab = A + (long)b * TT * TT;
  __shared__ float Ls[64][65];
  __shared__ float Sx[64][65];
  int tid = threadIdx.x;
  for (int idx = tid; idx < 4096; idx += 256) {
    int r = idx >> 6, c = idx & 63;
    Ls[r][c] = Wb[(long)(j0 + r) * TT + i0 + c];
  }
  __syncthreads();
  for (int idx = tid; idx < 4096; idx += 256) {
    int r = idx >> 6, c = idx & 63;
    int i = i0 + r, j = j0 + c;
    float a = Ab[(long)i * TT + j];
    float v = 0.f;
    if (j > 0) v = a * diag[b * TT + j];
    if (i > 0) v -= a * Ls[c][r];
    dxb[(long)b * 1048576 + (long)i * 1024 + j] = bf16rne(v);
    Sx[r][c] = v;
  }
  __syncthreads();
  float* dfb = dfout + (long)b * TT * 1025;
  unsigned short* dtb = dxTb + (long)b * 1048576;
  for (int idx = tid; idx < 4096; idx += 256) {
    int r = idx >> 6, c = idx & 63;
    float v = Sx[c][r];
    dfb[(long)(j0 + r) * 1025 + i0 + 1 + c] = v;
    dtb[(long)(j0 + r) * 1024 + i0 + c] = bf16rne(v);
  }
}

extern "C" void kernel_launch(void* const* d_in, const int* in_sizes, int n_in,
                              void* d_out, int out_size, void* d_ws, size_t ws_size,
                              hipStream_t stream){
  const float* input   = (const float*)d_in[0];
  const float* Wtp     = (const float*)d_in[1];
  const float* btp     = (const float*)d_in[2];
  const float* Wtc     = (const float*)d_in[3];
  const float* btc     = (const float*)d_in[4];
  const float* wfi     = (const float*)d_in[5];
  const float* Wbil    = (const float*)d_in[6];
  const float* exparam = (const float*)d_in[7];
  const float* Wfz     = (const float*)d_in[8];
  const float* bfz     = (const float*)d_in[9];

  if (ws_size < 150000000UL) return;

  float* ws   = (float*)d_ws;
  float* sem   = ws;                    // 4,194,304 f
  float* strv  = ws + 4194304;          // 4,194,304 f  [later: dxb bf16]
  float* Abuf  = ws + 8388608;          // 8,388,608 f  [later: finpb bf16]
  float* Wbuf  = ws + 16777216;         // 8,388,608 f
  unsigned short* strb = (unsigned short*)(ws + 25165824);
  unsigned short* tpb  = (unsigned short*)(ws + 27262976);
  unsigned short* tcb  = (unsigned short*)(ws + 29360128);
  unsigned short* tpwb = (unsigned short*)(ws + 31457280);
  unsigned short* wtpb = (unsigned short*)(ws + 33554432);
  unsigned short* wtcb = (unsigned short*)(ws + 33685504);
  unsigned short* wbilT= (unsigned short*)(ws + 33816576);
  unsigned short* wfzb = (unsigned short*)(ws + 33947648);
  float* fi    = ws + 34340864;         // 8192
  float* csp   = ws + 34349056;         // 65,536 (8 partials x 8192)
  float* d0    = ws + 34414592;         // 8192
  float* dg    = ws + 34422784;         // 8192
  float* Dinv  = ws + 34430976;         // 32,768
  float* Rnew  = ws + 34463744;         // 524,288
  unsigned short* ChA = (unsigned short*)(ws + 34988032);  // 8x1024x64 bf16
  unsigned short* ClA = (unsigned short*)(ws + 35250176);
  unsigned short* ChB = (unsigned short*)(ws + 35512320);
  unsigned short* ClB = (unsigned short*)(ws + 35774464);
  unsigned short* RTh = (unsigned short*)(ws + 36036608);
  unsigned short* RTl = (unsigned short*)(ws + 36298752);
  unsigned short* dxb   = (unsigned short*)strv;
  unsigned short* dxTb  = (unsigned short*)(ws + 25165824);
  unsigned short* semTb = (unsigned short*)(ws + 29360128);
  unsigned short* finpb = (unsigned short*)Abuf;

  float* outp = (float*)d_out;
  float* dfp  = outp + 4194304;

  split_k<<<8192, 256, 0, stream>>>(input, sem, strv);
  castrow_k<<<4096, 256, 0, stream>>>(strv, strb);
  castrow_k<<<256, 256, 0, stream>>>(Wtp, wtpb);
  castrow_k<<<256, 256, 0, stream>>>(Wtc, wtcb);
  castrow_k<<<768, 256, 0, stream>>>(Wfz, wfzb);
  castT_k<<<dim3(16,16,1), 256, 0, stream>>>(Wbil, wbilT, 512, 512, 0, 0);
  fi_k<<<2048, 256, 0, stream>>>(strv, wfi, fi);
  mgemm_k<1,1><<<dim3(4,64,1),256,0,stream>>>(strb, wtpb, tpb, 512, 512, 512, 512, 0,0,0, btp, nullptr,0,nullptr);
  mgemm_k<1,1><<<dim3(4,64,1),256,0,stream>>>(strb, wtcb, tcb, 512, 512, 512, 512, 0,0,0, btc, nullptr,0,nullptr);
  mgemm_k<0,1><<<dim3(4,64,1),256,0,stream>>>(tpb, wbilT, tpwb, 512, 512, 512, 512, 0,0,0, nullptr, nullptr,0,nullptr);
  mgemm_k<2,0><<<dim3(8,8,8),256,0,stream>>>(tpwb, tcb, Abuf, 512, 512, 512, 1024, 524288,524288,1048576, nullptr, nullptr,0,nullptr);
  castT_k<<<dim3(16,32,8), 256, 0, stream>>>(sem, semTb, 1024, 512, 524288, 524288);
  colsum_k<<<dim3(4,8,8),256,0,stream>>>(Abuf, csp);
  buildw_k<<<32768,256,0,stream>>>(Abuf, fi, csp, Wbuf, ChA, ClA);
  // blocked in-place Gauss-Jordan inverse; bf16x3 split-MFMA trailing update
  for (int s = 0; s < 16; ++s) {
    int k0 = s * NB;
    unsigned short* ChI = (s & 1) ? ChB : ChA;
    unsigned short* ClI = (s & 1) ? ClB : ClA;
    unsigned short* ChO = (s & 1) ? ChA : ChB;
    unsigned short* ClO = (s & 1) ? ClA : ClB;
    gj_dinv_k<<<8,256,0,stream>>>(Wbuf, Dinv, k0);
    gj_prep_k<<<dim3(64,8),256,0,stream>>>(Wbuf, Dinv, Rnew, RTh, RTl, k0);
    gupd_k<<<dim3(8,8,8),256,0,stream>>>(ChI, ClI, RTh, RTl, Rnew, Wbuf, ChO, ClO, k0);
  }
  ddiag_k<<<32,256,0,stream>>>(Wbuf, fi, d0, dg, dfp);
  dx_k<<<dim3(16,16,8),256,0,stream>>>(Abuf, Wbuf, dg, dfp, dxb, dxTb);
  semcopy_k<<<4096,256,0,stream>>>(sem, finpb);
  mgemm_k<4,1><<<dim3(4,8,8),256,0,stream>>>(dxTb, semTb, finpb + 512, 1024, 1024, 1024, 1536,
                                             1048576, 524288, 1572864, nullptr, d0, 1024, exparam);
  mgemm_k<0,1><<<dim3(4,8,8),256,0,stream>>>(dxb, semTb, finpb + 1024, 1024, 1024, 1024, 1536,
                                             1048576, 524288, 1572864, nullptr, nullptr,0,nullptr);
  mgemm_k<3,0><<<dim3(4,64,1),256,0,stream>>>(finpb, wfzb, outp, 1536, 1536, 1536, 512, 0,0,0, bfz, nullptr,0,nullptr);
}

// Round 8
// 1516.526 us; speedup vs baseline: 1.0502x; 1.0502x over previous
//
#include <hip/hip_runtime.h>
#include <math.h>

#define TT 1024
#define NB 64

typedef float f32x4 __attribute__((ext_vector_type(4)));
typedef __bf16 bf16x8 __attribute__((ext_vector_type(8)));

__device__ __forceinline__ float4 ld4(const float* p){ return *(const float4*)p; }
__device__ __forceinline__ unsigned short bf16rne(float x){
  unsigned u = __float_as_uint(x);
  return (unsigned short)((u + 0x7FFF + ((u >> 16) & 1)) >> 16);
}

// ================= bf16 MFMA GEMM: C = epi(A @ B^T_panels) =================
template<int EPI, int OUTBF>
__global__ __launch_bounds__(256)
void mgemm_k(const unsigned short* __restrict__ A, const unsigned short* __restrict__ B,
             void* __restrict__ Cv, int K, int lda, int ldb, int ldc,
             long sA, long sB, long sC,
             const float* __restrict__ bias,
             const float* __restrict__ e1, long sE1, const float* __restrict__ e2)
{
  const int bz = blockIdx.z;
  A += (long)bz * sA; B += (long)bz * sB;
  __shared__ char lds[16384];
  char* As = lds; char* Bs = lds + 8192;
  const int tid = threadIdx.x;
  const int l = tid & 63, wid = tid >> 6;
  const int wr = wid >> 1, wc = wid & 1;
  const int m0 = blockIdx.y * 128, n0 = blockIdx.x * 128;
  const int lrow = l & 15, lslot = (l >> 4) << 4;
  f32x4 acc[4][4] = {};

  for (int kk = 0; kk < K; kk += 32) {
#pragma unroll
    for (int i = 0; i < 2; ++i) {
      int idx = i * 256 + tid;
      int row = idx >> 2, c16 = (idx & 3) << 4;
      int sw = c16 ^ (((row >> 1) & 3) << 4);
      uint4 va = *(const uint4*)(A + (long)(m0 + row) * lda + kk + (c16 >> 1));
      *(uint4*)(As + row * 64 + sw) = va;
      uint4 vb = *(const uint4*)(B + (long)(n0 + row) * ldb + kk + (c16 >> 1));
      *(uint4*)(Bs + row * 64 + sw) = vb;
    }
    __syncthreads();
    bf16x8 af[4], bfr[4];
#pragma unroll
    for (int t = 0; t < 4; ++t) {
      int ra = wr * 64 + t * 16 + lrow;
      af[t]  = *(const bf16x8*)(As + ra * 64 + (lslot ^ (((ra >> 1) & 3) << 4)));
      int rb = wc * 64 + t * 16 + lrow;
      bfr[t] = *(const bf16x8*)(Bs + rb * 64 + (lslot ^ (((rb >> 1) & 3) << 4)));
    }
#pragma unroll
    for (int mi = 0; mi < 4; ++mi)
#pragma unroll
      for (int ni = 0; ni < 4; ++ni)
        acc[mi][ni] = __builtin_amdgcn_mfma_f32_16x16x32_bf16(af[mi], bfr[ni], acc[mi][ni], 0, 0, 0);
    __syncthreads();
  }

  float* Cf = (float*)Cv; unsigned short* Cb = (unsigned short*)Cv;
  if (OUTBF) Cb += (long)bz * sC; else Cf += (long)bz * sC;
  if (e1) e1 += (long)bz * sE1;
#pragma unroll
  for (int mi = 0; mi < 4; ++mi)
#pragma unroll
  for (int ni = 0; ni < 4; ++ni)
#pragma unroll
  for (int r = 0; r < 4; ++r) {
    int m = m0 + wr * 64 + mi * 16 + ((l >> 4) << 2) + r;
    int n = n0 + wc * 64 + ni * 16 + (l & 15);
    float v = acc[mi][ni][r];
    if (EPI == 1) v = tanhf(v + bias[n]);
    else if (EPI == 2) v = (m == n) ? 0.f : expf(tanhf(v));
    else if (EPI == 3) v = fmaxf(v + bias[n], 0.f);
    else if (EPI == 4) v = v + e1[m] * e2[n];
    if (OUTBF) Cb[(long)m * ldc + n] = bf16rne(v);
    else       Cf[(long)m * ldc + n] = v;
  }
}

// ---------------- feature split ----------------
__global__ void split_k(const float* __restrict__ in, float* __restrict__ sem, float* __restrict__ str){
  long row = blockIdx.x;
  int c = threadIdx.x << 2;
  float4 v = ld4(in + row * 1024 + c);
  float* dst;
  if (c < 256)      dst = sem + row * 512 + c;
  else if (c < 512) dst = str + row * 512 + (c - 256);
  else if (c < 768) dst = sem + row * 512 + 256 + (c - 512);
  else              dst = str + row * 512 + 256 + (c - 768);
  *(float4*)dst = v;
}

// ---------------- casts ----------------
__global__ void castrow_k(const float* __restrict__ src, unsigned short* __restrict__ dst){
  long i = ((long)blockIdx.x * 256 + threadIdx.x) << 2;
  float4 v = ld4(src + i);
  unsigned lo = bf16rne(v.x) | ((unsigned)bf16rne(v.y) << 16);
  unsigned hi = bf16rne(v.z) | ((unsigned)bf16rne(v.w) << 16);
  uint2 w; w.x = lo; w.y = hi;
  *(uint2*)(dst + i) = w;
}

__global__ __launch_bounds__(256) void castT_k(const float* __restrict__ src, unsigned short* __restrict__ dst,
                                               int R, int C, long sS, long sD){
  int b = blockIdx.z;
  src += (long)b * sS; dst += (long)b * sD;
  __shared__ float t[32][33];
  int r0 = blockIdx.y * 32, c0 = blockIdx.x * 32;
  int tx = threadIdx.x & 31, ty = threadIdx.x >> 5;
#pragma unroll
  for (int j = 0; j < 32; j += 8)
    t[ty + j][tx] = src[(long)(r0 + ty + j) * C + c0 + tx];
  __syncthreads();
#pragma unroll
  for (int j = 0; j < 32; j += 8)
    dst[(long)(c0 + ty + j) * R + r0 + tx] = bf16rne(t[tx][ty + j]);
}

__global__ void semcopy_k(const float* __restrict__ sem, unsigned short* __restrict__ finpb){
  long idx = ((long)blockIdx.x * 256 + threadIdx.x) << 2;
  long row = idx >> 9; int col = (int)(idx & 511);
  float4 v = ld4(sem + idx);
  unsigned lo = bf16rne(v.x) | ((unsigned)bf16rne(v.y) << 16);
  unsigned hi = bf16rne(v.z) | ((unsigned)bf16rne(v.w) << 16);
  uint2 w; w.x = lo; w.y = hi;
  *(uint2*)(finpb + row * 1536 + col) = w;
}

// ---------------- f_i = exp(tanh(str . wfi)) ----------------
__global__ void fi_k(const float* __restrict__ str, const float* __restrict__ wfi, float* __restrict__ fi){
  int row = blockIdx.x * 4 + (threadIdx.x >> 6);
  int lane = threadIdx.x & 63;
  const float* p = str + (long)row * 512;
  float acc = 0.f;
  for (int c = lane; c < 512; c += 64) acc = fmaf(p[c], wfi[c], acc);
  for (int off = 32; off; off >>= 1) acc += __shfl_down(acc, off, 64);
  if (lane == 0) fi[row] = expf(tanhf(acc));
}

// ---------------- column sums (8 row-chunk partials) ----------------
__global__ void colsum_k(const float* __restrict__ A, float* __restrict__ csp){
  int b = blockIdx.y, rc = blockIdx.z;
  int j = blockIdx.x * 256 + threadIdx.x;
  const float* p = A + (long)b * TT * TT + (long)rc * 128 * TT + j;
  float acc = 0.f;
  for (int i = 0; i < 128; ++i) acc += p[(long)i * TT];
  csp[rc * 8192 + b * TT + j] = acc;
}

// ---------------- build L_bar (+ emit Cold0 hi/lo) ----------------
__global__ void buildw_k(const float* __restrict__ A, const float* __restrict__ fi,
                         const float* __restrict__ csp, float* __restrict__ W,
                         unsigned short* __restrict__ Ch0, unsigned short* __restrict__ Cl0){
  long idx = (long)blockIdx.x * 256 + threadIdx.x;
  long b = idx >> 20;
  long r = idx & 1048575;
  int i = (int)(r >> 10), j = (int)(r & 1023);
  float v;
  if (i == 0)      v = fi[b * TT + j];
  else if (i == j) {
    v = 0.f;
#pragma unroll
    for (int c = 0; c < 8; ++c) v += csp[c * 8192 + b * TT + j];
  }
  else             v = -A[idx];
  W[idx] = v;
  if (j < 64) {
    unsigned short h = bf16rne(v);
    float hf = __uint_as_float((unsigned)h << 16);
    Ch0[b * 65536 + i * 64 + j] = h;
    Cl0[b * 65536 + i * 64 + j] = bf16rne(v - hf);
  }
}

// ---------------- GJ: standalone 64x64 diag inverse (step 0 only) ----------------
__global__ __launch_bounds__(256, 1) void gj_dinv_k(const float* __restrict__ W, float* __restrict__ Dinv, int k0){
  __shared__ float Pa[64][68];
  __shared__ float Pb[64][68];
  int b = blockIdx.x;
  int tid = threadIdx.x;
  int r = tid & 63, q16 = (tid >> 6) << 4;
  const float* Wb = W + (long)b * TT * TT + (long)(k0 + r) * TT + k0 + q16;
#pragma unroll
  for (int j = 0; j < 16; j += 4) *(float4*)&Pa[r][q16 + j] = ld4(Wb + j);
  __syncthreads();
#define DSTEP(kv, SRC, DST) { \
    int k_ = (kv); \
    float pk = SRC[k_][k_]; \
    float f  = SRC[r][k_]; \
    float pr = 1.f / pk; \
    bool piv = (r == k_); \
    float t = piv ? -pr : f * pr; \
    float ov[16]; \
    _Pragma("unroll") \
    for (int c = 0; c < 16; ++c) { \
      float pv = SRC[k_][q16 + c]; \
      float z = piv ? 0.f : SRC[r][q16 + c]; \
      float val = fmaf(-t, pv, z); \
      if (q16 + c == k_) val = -t; \
      ov[c] = val; \
    } \
    _Pragma("unroll") \
    for (int j = 0; j < 16; j += 4) *(float4*)&DST[r][q16 + j] = *(float4*)&ov[j]; \
    __syncthreads(); }
  for (int k = 0; k < 64; k += 2) {
    DSTEP(k, Pa, Pb)
    DSTEP(k + 1, Pb, Pa)
  }
  float* Db = Dinv + b * 4096 + r * 64 + q16;
#pragma unroll
  for (int j = 0; j < 16; j += 4) *(float4*)(Db + j) = *(float4*)&Pa[r][q16 + j];
}

// ---------------- GJ: Rnew = Dinv @ W[K,:] (cols K := Dinv), coalesced emits ----------------
// grid (8 col-chunks, 8 batches), 256 thr. Emits Rnew f32 rows + RT hi/lo bf16 rows.
__global__ __launch_bounds__(256) void gj_prep_k(const float* __restrict__ W, const float* __restrict__ Dinv,
                                                 float* __restrict__ Rnew,
                                                 unsigned short* __restrict__ RTh, unsigned short* __restrict__ RTl,
                                                 int k0){
  int b = blockIdx.y;
  int J = blockIdx.x * 128;
  __shared__ float S[64][132];   // W-row staging, then output tile
  __shared__ float DT[64][64];   // Dinv transposed: DT[q][p]
  const float* Wb = W + (long)b * 1048576 + (long)k0 * 1024 + J;
  int tid = threadIdx.x;
  for (int i = tid; i < 2048; i += 256) {
    int q = i >> 5, j4 = (i & 31) << 2;
    *(float4*)&S[q][j4] = ld4(Wb + (long)q * 1024 + j4);
  }
  {
    int p = tid & 63, qg = (tid >> 6) << 4;
    const float* Dp = Dinv + b * 4096 + p * 64 + qg;
#pragma unroll
    for (int e = 0; e < 16; e += 4) {
      float4 v = ld4(Dp + e);
      DT[qg + e][p] = v.x; DT[qg + e + 1][p] = v.y;
      DT[qg + e + 2][p] = v.z; DT[qg + e + 3][p] = v.w;
    }
  }
  __syncthreads();
  int p = tid & 63, cg = (tid >> 6) << 5;
  float acc[32] = {};
  for (int q = 0; q < 64; ++q) {
    float d = DT[q][p];
#pragma unroll
    for (int c = 0; c < 32; ++c) acc[c] = fmaf(d, S[q][cg + c], acc[c]);
  }
  __syncthreads();
#pragma unroll
  for (int c = 0; c < 32; ++c) {
    int jg = J + cg + c;
    float v = acc[c];
    if (jg >= k0 && jg < k0 + 64) v = DT[jg - k0][p];
    S[p][cg + c] = v;
  }
  __syncthreads();
  float* Rb = Rnew + (long)b * 65536 + J;
  for (int i = tid; i < 2048; i += 256) {
    int r = i >> 5, j4 = (i & 31) << 2;
    *(float4*)(Rb + (long)r * 1024 + j4) = *(float4*)&S[r][j4];
  }
  unsigned short* th = RTh + (long)b * 65536 + (long)J * 64;
  unsigned short* tl = RTl + (long)b * 65536 + (long)J * 64;
  for (int i = tid; i < 8192; i += 256) {
    int jl = i >> 6, pp = i & 63;
    float v = S[pp][jl];
    unsigned short h = bf16rne(v);
    float hf = __uint_as_float((unsigned)h << 16);
    th[i] = h;
    tl[i] = bf16rne(v - hf);
  }
}

// ---------------- GJ trailing update (bf16x3 MFMA, LDS-staged) + fused next-diag inverse ----------------
__global__ __launch_bounds__(256) void gupd_k(const unsigned short* __restrict__ Ch, const unsigned short* __restrict__ Cl,
                                              const unsigned short* __restrict__ RTh, const unsigned short* __restrict__ RTl,
                                              const float* __restrict__ Rnew, float* __restrict__ W,
                                              unsigned short* __restrict__ ChN, unsigned short* __restrict__ ClN,
                                              float* __restrict__ Dinv, int k0){
  __shared__ char lds[65536];   // 4 panels [128][64] bf16, XOR-swizzled; later aliased by dinv P
  int b = blockIdx.z;
  const float* Rb = Rnew + (long)b * 65536;
  float* Wb = W + (long)b * 1048576;
  unsigned short* CnH = ChN + (long)b * 65536;
  unsigned short* CnL = ClN + (long)b * 65536;
  const int tid = threadIdx.x, l = tid & 63, wid = tid >> 6;
  const int wr = wid >> 1, wc = wid & 1;
  const int m0 = blockIdx.y * 128, n0 = blockIdx.x * 128;
  // ---- stage 4 panels (each 128 rows x 128 B), coalesced, swizzle byte^=((row&7)<<4)
  {
    const unsigned short* srcs[4] = {
      Ch  + (long)b * 65536 + (long)m0 * 64,
      Cl  + (long)b * 65536 + (long)m0 * 64,
      RTh + (long)b * 65536 + (long)n0 * 64,
      RTl + (long)b * 65536 + (long)n0 * 64 };
#pragma unroll
    for (int pnl = 0; pnl < 4; ++pnl) {
      const char* s = (const char*)srcs[pnl];
      char* d = lds + pnl * 16384;
      for (int i = tid; i < 1024; i += 256) {
        int row = i >> 3, c16 = (i & 7) << 4;
        uint4 v = *(const uint4*)(s + row * 128 + c16);
        *(uint4*)(d + row * 128 + (c16 ^ ((row & 7) << 4))) = v;
      }
    }
  }
  __syncthreads();
  const int lrow = l & 15, kc16 = (l >> 4) << 4;
  f32x4 acc[4][4] = {};
#pragma unroll
  for (int kk = 0; kk < 2; ++kk) {      // two K=32 chunks (byte offset kk*64)
    bf16x8 ah[4], al4[4], bh[4], bl4[4];
#pragma unroll
    for (int t = 0; t < 4; ++t) {
      int ra = wr * 64 + t * 16 + lrow;
      int offa = (ra * 128 + kk * 64 + kc16) ^ ((ra & 7) << 4);
      ah[t]  = *(const bf16x8*)(lds + offa);
      al4[t] = *(const bf16x8*)(lds + 16384 + offa);
      int rb = wc * 64 + t * 16 + lrow;
      int offb = (rb * 128 + kk * 64 + kc16) ^ ((rb & 7) << 4);
      bh[t]  = *(const bf16x8*)(lds + 32768 + offb);
      bl4[t] = *(const bf16x8*)(lds + 49152 + offb);
    }
#pragma unroll
    for (int mi = 0; mi < 4; ++mi)
#pragma unroll
      for (int ni = 0; ni < 4; ++ni) {
        acc[mi][ni] = __builtin_amdgcn_mfma_f32_16x16x32_bf16(ah[mi],  bh[ni],  acc[mi][ni], 0, 0, 0);
        acc[mi][ni] = __builtin_amdgcn_mfma_f32_16x16x32_bf16(ah[mi],  bl4[ni], acc[mi][ni], 0, 0, 0);
        acc[mi][ni] = __builtin_amdgcn_mfma_f32_16x16x32_bf16(al4[mi], bh[ni],  acc[mi][ni], 0, 0, 0);
      }
  }
  __syncthreads();   // staging dead; P may alias it below
  // ---- epilogue (+ owner block captures next diag quadrant into LDS)
  const int dbase = k0 + 64;
  const bool diagOwner = (dbase < 1024) && (blockIdx.y == (dbase >> 7)) && (blockIdx.x == (dbase >> 7));
  const int qr = (dbase >> 6) & 1;
  float (*P)[68] = (float(*)[68])lds;
  bool ownWave = diagOwner && (wr == qr) && (wc == qr);
#pragma unroll
  for (int mi = 0; mi < 4; ++mi)
#pragma unroll
  for (int ni = 0; ni < 4; ++ni)
#pragma unroll
  for (int r = 0; r < 4; ++r) {
    int m = m0 + wr * 64 + mi * 16 + ((l >> 4) << 2) + r;
    int n = n0 + wc * 64 + ni * 16 + (l & 15);
    bool rowK = (m >= k0 && m < k0 + 64);
    bool colK = (n >= k0 && n < k0 + 64);
    float v;
    if (rowK)      v = Rb[(long)(m - k0) * 1024 + n];
    else if (colK) v = -acc[mi][ni][r];
    else           v = Wb[(long)m * 1024 + n] - acc[mi][ni][r];
    Wb[(long)m * 1024 + n] = v;
    int cn = n - k0 - 64;
    if (cn >= 0 && cn < 64) {
      unsigned short h = bf16rne(v);
      float hf = __uint_as_float((unsigned)h << 16);
      CnH[(long)m * 64 + cn] = h;
      CnL[(long)m * 64 + cn] = bf16rne(v - hf);
    }
    if (ownWave) P[m - dbase][n - dbase] = v;
  }
  // ---- fused inversion of the next diag block (owner block only; hidden behind other blocks)
  if (diagOwner) {
    __syncthreads();
    int r = tid & 63, q16 = (tid >> 6) << 4;
    for (int k = 0; k < 64; ++k) {
      float pk = P[k][k];
      float f  = P[r][k];
      float pv[16], ov[16];
#pragma unroll
      for (int j = 0; j < 16; j += 4) {
        *(float4*)&pv[j] = *(float4*)&P[k][q16 + j];
        *(float4*)&ov[j] = *(float4*)&P[r][q16 + j];
      }
      __syncthreads();
      float pr = 1.f / pk;
      bool piv = (r == k);
      float t = piv ? -pr : f * pr;
#pragma unroll
      for (int c = 0; c < 16; ++c) {
        float z = piv ? 0.f : ov[c];
        float val = fmaf(-t, pv[c], z);
        if (q16 + c == k) val = -t;
        ov[c] = val;
      }
#pragma unroll
      for (int j = 0; j < 16; j += 4) *(float4*)&P[r][q16 + j] = *(float4*)&ov[j];
      __syncthreads();
    }
    float* Db = Dinv + b * 4096 + r * 64 + q16;
#pragma unroll
    for (int j = 0; j < 16; j += 4) *(float4*)(Db + j) = *(float4*)&P[r][q16 + j];
  }
}

// ---------------- d0, diag, df col 0 ----------------
__global__ void ddiag_k(const float* __restrict__ W, const float* __restrict__ fi,
                        float* __restrict__ d0, float* __restrict__ diag, float* __restrict__ dfout){
  int t = blockIdx.x * 256 + threadIdx.x;
  int b = t >> 10, i = t & 1023;
  const float* Wb = W + (long)b * TT * TT;
  float dv = fi[t] * Wb[(long)i * TT];
  d0[t] = dv;
  diag[t] = Wb[(long)i * TT + i];
  dfout[(long)b * TT * 1025 + (long)i * 1025] = dv;
}

// ---------------- dx: compute, emit bf16 dx + bf16 dx^T + df store ----------------
__global__ __launch_bounds__(256) void dx_k(const float* __restrict__ A, const float* __restrict__ W,
                                            const float* __restrict__ diag, float* __restrict__ dfout,
                                            unsigned short* __restrict__ dxb, unsigned short* __restrict__ dxTb){
  int b = blockIdx.z;
  int i0 = blockIdx.y * 64, j0 = blockIdx.x * 64;
  const float* Wb = W + (long)b * TT * TT;
  const float* Ab = A + (long)b * TT * TT;
  __shared__ float Ls[64][65];
  __shared__ float Sx[64][65];
  int tid = threadIdx.x;
  for (int idx = tid; idx < 4096; idx += 256) {
    int r = idx >> 6, c = idx & 63;
    Ls[r][c] = Wb[(long)(j0 + r) * TT + i0 + c];
  }
  __syncthreads();
  for (int idx = tid; idx < 4096; idx += 256) {
    int r = idx >> 6, c = idx & 63;
    int i = i0 + r, j = j0 + c;
    float a = Ab[(long)i * TT + j];
    float v = 0.f;
    if (j > 0) v = a * diag[b * TT + j];
    if (i > 0) v -= a * Ls[c][r];
    dxb[(long)b * 1048576 + (long)i * 1024 + j] = bf16rne(v);
    Sx[r][c] = v;
  }
  __syncthreads();
  float* dfb = dfout + (long)b * TT * 1025;
  unsigned short* dtb = dxTb + (long)b * 1048576;
  for (int idx = tid; idx < 4096; idx += 256) {
    int r = idx >> 6, c = idx & 63;
    float v = Sx[c][r];
    dfb[(long)(j0 + r) * 1025 + i0 + 1 + c] = v;
    dtb[(long)(j0 + r) * 1024 + i0 + c] = bf16rne(v);
  }
}

extern "C" void kernel_launch(void* const* d_in, const int* in_sizes, int n_in,
                              void* d_out, int out_size, void* d_ws, size_t ws_size,
                              hipStream_t stream){
  const float* input   = (const float*)d_in[0];
  const float* Wtp     = (const float*)d_in[1];
  const float* btp     = (const float*)d_in[2];
  const float* Wtc     = (const float*)d_in[3];
  const float* btc     = (const float*)d_in[4];
  const float* wfi     = (const float*)d_in[5];
  const float* Wbil    = (const float*)d_in[6];
  const float* exparam = (const float*)d_in[7];
  const float* Wfz     = (const float*)d_in[8];
  const float* bfz     = (const float*)d_in[9];

  if (ws_size < 150000000UL) return;

  float* ws   = (float*)d_ws;
  float* sem   = ws;                    // 4,194,304 f
  float* strv  = ws + 4194304;          // 4,194,304 f  [later: dxb bf16]
  float* Abuf  = ws + 8388608;          // 8,388,608 f  [later: finpb bf16]
  float* Wbuf  = ws + 16777216;         // 8,388,608 f
  unsigned short* strb = (unsigned short*)(ws + 25165824);
  unsigned short* tpb  = (unsigned short*)(ws + 27262976);
  unsigned short* tcb  = (unsigned short*)(ws + 29360128);
  unsigned short* tpwb = (unsigned short*)(ws + 31457280);
  unsigned short* wtpb = (unsigned short*)(ws + 33554432);
  unsigned short* wtcb = (unsigned short*)(ws + 33685504);
  unsigned short* wbilT= (unsigned short*)(ws + 33816576);
  unsigned short* wfzb = (unsigned short*)(ws + 33947648);
  float* fi    = ws + 34340864;         // 8192
  float* csp   = ws + 34349056;         // 65,536
  float* d0    = ws + 34414592;         // 8192
  float* dg    = ws + 34422784;         // 8192
  float* Dinv  = ws + 34430976;         // 32,768
  float* Rnew  = ws + 34463744;         // 524,288
  unsigned short* ChA = (unsigned short*)(ws + 34988032);  // 8x1024x64 bf16
  unsigned short* ClA = (unsigned short*)(ws + 35250176);
  unsigned short* ChB = (unsigned short*)(ws + 35512320);
  unsigned short* ClB = (unsigned short*)(ws + 35774464);
  unsigned short* RTh = (unsigned short*)(ws + 36036608);
  unsigned short* RTl = (unsigned short*)(ws + 36298752);
  unsigned short* dxb   = (unsigned short*)strv;
  unsigned short* dxTb  = (unsigned short*)(ws + 25165824);
  unsigned short* semTb = (unsigned short*)(ws + 29360128);
  unsigned short* finpb = (unsigned short*)Abuf;

  float* outp = (float*)d_out;
  float* dfp  = outp + 4194304;

  split_k<<<8192, 256, 0, stream>>>(input, sem, strv);
  castrow_k<<<4096, 256, 0, stream>>>(strv, strb);
  castrow_k<<<256, 256, 0, stream>>>(Wtp, wtpb);
  castrow_k<<<256, 256, 0, stream>>>(Wtc, wtcb);
  castrow_k<<<768, 256, 0, stream>>>(Wfz, wfzb);
  castT_k<<<dim3(16,16,1), 256, 0, stream>>>(Wbil, wbilT, 512, 512, 0, 0);
  fi_k<<<2048, 256, 0, stream>>>(strv, wfi, fi);
  mgemm_k<1,1><<<dim3(4,64,1),256,0,stream>>>(strb, wtpb, tpb, 512, 512, 512, 512, 0,0,0, btp, nullptr,0,nullptr);
  mgemm_k<1,1><<<dim3(4,64,1),256,0,stream>>>(strb, wtcb, tcb, 512, 512, 512, 512, 0,0,0, btc, nullptr,0,nullptr);
  mgemm_k<0,1><<<dim3(4,64,1),256,0,stream>>>(tpb, wbilT, tpwb, 512, 512, 512, 512, 0,0,0, nullptr, nullptr,0,nullptr);
  mgemm_k<2,0><<<dim3(8,8,8),256,0,stream>>>(tpwb, tcb, Abuf, 512, 512, 512, 1024, 524288,524288,1048576, nullptr, nullptr,0,nullptr);
  castT_k<<<dim3(16,32,8), 256, 0, stream>>>(sem, semTb, 1024, 512, 524288, 524288);
  colsum_k<<<dim3(4,8,8),256,0,stream>>>(Abuf, csp);
  buildw_k<<<32768,256,0,stream>>>(Abuf, fi, csp, Wbuf, ChA, ClA);
  // blocked in-place Gauss-Jordan: 1 standalone dinv + {prep, gupd(+fused next dinv)} x 16
  gj_dinv_k<<<8,256,0,stream>>>(Wbuf, Dinv, 0);
  for (int s = 0; s < 16; ++s) {
    int k0 = s * NB;
    unsigned short* ChI = (s & 1) ? ChB : ChA;
    unsigned short* ClI = (s & 1) ? ClB : ClA;
    unsigned short* ChO = (s & 1) ? ChA : ChB;
    unsigned short* ClO = (s & 1) ? ClA : ClB;
    gj_prep_k<<<dim3(8,8),256,0,stream>>>(Wbuf, Dinv, Rnew, RTh, RTl, k0);
    gupd_k<<<dim3(8,8,8),256,0,stream>>>(ChI, ClI, RTh, RTl, Rnew, Wbuf, ChO, ClO, Dinv, k0);
  }
  ddiag_k<<<32,256,0,stream>>>(Wbuf, fi, d0, dg, dfp);
  dx_k<<<dim3(16,16,8),256,0,stream>>>(Abuf, Wbuf, dg, dfp, dxb, dxTb);
  semcopy_k<<<4096,256,0,stream>>>(sem, finpb);
  mgemm_k<4,1><<<dim3(4,8,8),256,0,stream>>>(dxTb, semTb, finpb + 512, 1024, 1024, 1024, 1536,
                                             1048576, 524288, 1572864, nullptr, d0, 1024, exparam);
  mgemm_k<0,1><<<dim3(4,8,8),256,0,stream>>>(dxb, semTb, finpb + 1024, 1024, 1024, 1024, 1536,
                                             1048576, 524288, 1572864, nullptr, nullptr,0,nullptr);
  mgemm_k<3,0><<<dim3(4,64,1),256,0,stream>>>(finpb, wfzb, outp, 1536, 1536, 1536, 512, 0,0,0, bfz, nullptr,0,nullptr);
}

// Round 9
// 1347.511 us; speedup vs baseline: 1.1820x; 1.1254x over previous
//
#include <hip/hip_runtime.h>
#include <math.h>

#define TT 1024
#define NB 64

typedef float f32x4 __attribute__((ext_vector_type(4)));
typedef __bf16 bf16x8 __attribute__((ext_vector_type(8)));

__device__ __forceinline__ float4 ld4(const float* p){ return *(const float4*)p; }
__device__ __forceinline__ unsigned short bf16rne(float x){
  unsigned u = __float_as_uint(x);
  return (unsigned short)((u + 0x7FFF + ((u >> 16) & 1)) >> 16);
}

// ================= bf16 MFMA GEMM: C = epi(A @ B^T_panels) =================
template<int EPI, int OUTBF>
__global__ __launch_bounds__(256)
void mgemm_k(const unsigned short* __restrict__ A, const unsigned short* __restrict__ B,
             void* __restrict__ Cv, int K, int lda, int ldb, int ldc,
             long sA, long sB, long sC,
             const float* __restrict__ bias,
             const float* __restrict__ e1, long sE1, const float* __restrict__ e2)
{
  const int bz = blockIdx.z;
  A += (long)bz * sA; B += (long)bz * sB;
  __shared__ char lds[16384];
  char* As = lds; char* Bs = lds + 8192;
  const int tid = threadIdx.x;
  const int l = tid & 63, wid = tid >> 6;
  const int wr = wid >> 1, wc = wid & 1;
  const int m0 = blockIdx.y * 128, n0 = blockIdx.x * 128;
  const int lrow = l & 15, lslot = (l >> 4) << 4;
  f32x4 acc[4][4] = {};

  for (int kk = 0; kk < K; kk += 32) {
#pragma unroll
    for (int i = 0; i < 2; ++i) {
      int idx = i * 256 + tid;
      int row = idx >> 2, c16 = (idx & 3) << 4;
      int sw = c16 ^ (((row >> 1) & 3) << 4);
      uint4 va = *(const uint4*)(A + (long)(m0 + row) * lda + kk + (c16 >> 1));
      *(uint4*)(As + row * 64 + sw) = va;
      uint4 vb = *(const uint4*)(B + (long)(n0 + row) * ldb + kk + (c16 >> 1));
      *(uint4*)(Bs + row * 64 + sw) = vb;
    }
    __syncthreads();
    bf16x8 af[4], bfr[4];
#pragma unroll
    for (int t = 0; t < 4; ++t) {
      int ra = wr * 64 + t * 16 + lrow;
      af[t]  = *(const bf16x8*)(As + ra * 64 + (lslot ^ (((ra >> 1) & 3) << 4)));
      int rb = wc * 64 + t * 16 + lrow;
      bfr[t] = *(const bf16x8*)(Bs + rb * 64 + (lslot ^ (((rb >> 1) & 3) << 4)));
    }
#pragma unroll
    for (int mi = 0; mi < 4; ++mi)
#pragma unroll
      for (int ni = 0; ni < 4; ++ni)
        acc[mi][ni] = __builtin_amdgcn_mfma_f32_16x16x32_bf16(af[mi], bfr[ni], acc[mi][ni], 0, 0, 0);
    __syncthreads();
  }

  float* Cf = (float*)Cv; unsigned short* Cb = (unsigned short*)Cv;
  if (OUTBF) Cb += (long)bz * sC; else Cf += (long)bz * sC;
  if (e1) e1 += (long)bz * sE1;
#pragma unroll
  for (int mi = 0; mi < 4; ++mi)
#pragma unroll
  for (int ni = 0; ni < 4; ++ni)
#pragma unroll
  for (int r = 0; r < 4; ++r) {
    int m = m0 + wr * 64 + mi * 16 + ((l >> 4) << 2) + r;
    int n = n0 + wc * 64 + ni * 16 + (l & 15);
    float v = acc[mi][ni][r];
    if (EPI == 1) v = tanhf(v + bias[n]);
    else if (EPI == 2) v = (m == n) ? 0.f : expf(tanhf(v));
    else if (EPI == 3) v = fmaxf(v + bias[n], 0.f);
    else if (EPI == 4) v = v + e1[m] * e2[n];
    if (OUTBF) Cb[(long)m * ldc + n] = bf16rne(v);
    else       Cf[(long)m * ldc + n] = v;
  }
}

// ---------------- feature split ----------------
__global__ void split_k(const float* __restrict__ in, float* __restrict__ sem, float* __restrict__ str){
  long row = blockIdx.x;
  int c = threadIdx.x << 2;
  float4 v = ld4(in + row * 1024 + c);
  float* dst;
  if (c < 256)      dst = sem + row * 512 + c;
  else if (c < 512) dst = str + row * 512 + (c - 256);
  else if (c < 768) dst = sem + row * 512 + 256 + (c - 512);
  else              dst = str + row * 512 + 256 + (c - 768);
  *(float4*)dst = v;
}

// ---------------- casts ----------------
__global__ void castrow_k(const float* __restrict__ src, unsigned short* __restrict__ dst){
  long i = ((long)blockIdx.x * 256 + threadIdx.x) << 2;
  float4 v = ld4(src + i);
  unsigned lo = bf16rne(v.x) | ((unsigned)bf16rne(v.y) << 16);
  unsigned hi = bf16rne(v.z) | ((unsigned)bf16rne(v.w) << 16);
  uint2 w; w.x = lo; w.y = hi;
  *(uint2*)(dst + i) = w;
}

__global__ __launch_bounds__(256) void castT_k(const float* __restrict__ src, unsigned short* __restrict__ dst,
                                               int R, int C, long sS, long sD){
  int b = blockIdx.z;
  src += (long)b * sS; dst += (long)b * sD;
  __shared__ float t[32][33];
  int r0 = blockIdx.y * 32, c0 = blockIdx.x * 32;
  int tx = threadIdx.x & 31, ty = threadIdx.x >> 5;
#pragma unroll
  for (int j = 0; j < 32; j += 8)
    t[ty + j][tx] = src[(long)(r0 + ty + j) * C + c0 + tx];
  __syncthreads();
#pragma unroll
  for (int j = 0; j < 32; j += 8)
    dst[(long)(c0 + ty + j) * R + r0 + tx] = bf16rne(t[tx][ty + j]);
}

__global__ void semcopy_k(const float* __restrict__ sem, unsigned short* __restrict__ finpb){
  long idx = ((long)blockIdx.x * 256 + threadIdx.x) << 2;
  long row = idx >> 9; int col = (int)(idx & 511);
  float4 v = ld4(sem + idx);
  unsigned lo = bf16rne(v.x) | ((unsigned)bf16rne(v.y) << 16);
  unsigned hi = bf16rne(v.z) | ((unsigned)bf16rne(v.w) << 16);
  uint2 w; w.x = lo; w.y = hi;
  *(uint2*)(finpb + row * 1536 + col) = w;
}

// ---------------- f_i = exp(tanh(str . wfi)) ----------------
__global__ void fi_k(const float* __restrict__ str, const float* __restrict__ wfi, float* __restrict__ fi){
  int row = blockIdx.x * 4 + (threadIdx.x >> 6);
  int lane = threadIdx.x & 63;
  const float* p = str + (long)row * 512;
  float acc = 0.f;
  for (int c = lane; c < 512; c += 64) acc = fmaf(p[c], wfi[c], acc);
  for (int off = 32; off; off >>= 1) acc += __shfl_down(acc, off, 64);
  if (lane == 0) fi[row] = expf(tanhf(acc));
}

// ---------------- column sums (8 row-chunk partials) ----------------
__global__ void colsum_k(const float* __restrict__ A, float* __restrict__ csp){
  int b = blockIdx.y, rc = blockIdx.z;
  int j = blockIdx.x * 256 + threadIdx.x;
  const float* p = A + (long)b * TT * TT + (long)rc * 128 * TT + j;
  float acc = 0.f;
  for (int i = 0; i < 128; ++i) acc += p[(long)i * TT];
  csp[rc * 8192 + b * TT + j] = acc;
}

// ---------------- build L_bar (+ emit Cold0 hi/lo) ----------------
__global__ void buildw_k(const float* __restrict__ A, const float* __restrict__ fi,
                         const float* __restrict__ csp, float* __restrict__ W,
                         unsigned short* __restrict__ Ch0, unsigned short* __restrict__ Cl0){
  long idx = (long)blockIdx.x * 256 + threadIdx.x;
  long b = idx >> 20;
  long r = idx & 1048575;
  int i = (int)(r >> 10), j = (int)(r & 1023);
  float v;
  if (i == 0)      v = fi[b * TT + j];
  else if (i == j) {
    v = 0.f;
#pragma unroll
    for (int c = 0; c < 8; ++c) v += csp[c * 8192 + b * TT + j];
  }
  else             v = -A[idx];
  W[idx] = v;
  if (j < 64) {
    unsigned short h = bf16rne(v);
    float hf = __uint_as_float((unsigned)h << 16);
    Ch0[b * 65536 + i * 64 + j] = h;
    Cl0[b * 65536 + i * 64 + j] = bf16rne(v - hf);
  }
}

// ---------------- GJ: standalone 64x64 diag inverse (every step) ----------------
__global__ __launch_bounds__(256, 1) void gj_dinv_k(const float* __restrict__ W, float* __restrict__ Dinv, int k0){
  __shared__ float Pa[64][68];
  __shared__ float Pb[64][68];
  int b = blockIdx.x;
  int tid = threadIdx.x;
  int r = tid & 63, q16 = (tid >> 6) << 4;
  const float* Wb = W + (long)b * TT * TT + (long)(k0 + r) * TT + k0 + q16;
#pragma unroll
  for (int j = 0; j < 16; j += 4) *(float4*)&Pa[r][q16 + j] = ld4(Wb + j);
  __syncthreads();
#define DSTEP(kv, SRC, DST) { \
    int k_ = (kv); \
    float pk = SRC[k_][k_]; \
    float f  = SRC[r][k_]; \
    float pr = 1.f / pk; \
    bool piv = (r == k_); \
    float t = piv ? -pr : f * pr; \
    float ov[16]; \
    _Pragma("unroll") \
    for (int c = 0; c < 16; ++c) { \
      float pv = SRC[k_][q16 + c]; \
      float z = piv ? 0.f : SRC[r][q16 + c]; \
      float val = fmaf(-t, pv, z); \
      if (q16 + c == k_) val = -t; \
      ov[c] = val; \
    } \
    _Pragma("unroll") \
    for (int j = 0; j < 16; j += 4) *(float4*)&DST[r][q16 + j] = *(float4*)&ov[j]; \
    __syncthreads(); }
  for (int k = 0; k < 64; k += 2) {
    DSTEP(k, Pa, Pb)
    DSTEP(k + 1, Pb, Pa)
  }
  float* Db = Dinv + b * 4096 + r * 64 + q16;
#pragma unroll
  for (int j = 0; j < 16; j += 4) *(float4*)(Db + j) = *(float4*)&Pa[r][q16 + j];
}

// ---------------- GJ: Rnew = Dinv @ W[K,:] (cols K := Dinv), coalesced emits ----------------
// grid (8 batches-x, 8 col-chunks-y), 256 thr. Batch pinned to XCD via blockIdx.x.
__global__ __launch_bounds__(256) void gj_prep_k(const float* __restrict__ W, const float* __restrict__ Dinv,
                                                 float* __restrict__ Rnew,
                                                 unsigned short* __restrict__ RTh, unsigned short* __restrict__ RTl,
                                                 int k0){
  int b = blockIdx.x;
  int J = blockIdx.y * 128;
  __shared__ float S[64][132];
  __shared__ float DT[64][64];
  const float* Wb = W + (long)b * 1048576 + (long)k0 * 1024 + J;
  int tid = threadIdx.x;
  for (int i = tid; i < 2048; i += 256) {
    int q = i >> 5, j4 = (i & 31) << 2;
    *(float4*)&S[q][j4] = ld4(Wb + (long)q * 1024 + j4);
  }
  {
    int p = tid & 63, qg = (tid >> 6) << 4;
    const float* Dp = Dinv + b * 4096 + p * 64 + qg;
#pragma unroll
    for (int e = 0; e < 16; e += 4) {
      float4 v = ld4(Dp + e);
      DT[qg + e][p] = v.x; DT[qg + e + 1][p] = v.y;
      DT[qg + e + 2][p] = v.z; DT[qg + e + 3][p] = v.w;
    }
  }
  __syncthreads();
  int p = tid & 63, cg = (tid >> 6) << 5;
  float acc[32] = {};
  for (int q = 0; q < 64; ++q) {
    float d = DT[q][p];
#pragma unroll
    for (int c = 0; c < 32; ++c) acc[c] = fmaf(d, S[q][cg + c], acc[c]);
  }
  __syncthreads();
#pragma unroll
  for (int c = 0; c < 32; ++c) {
    int jg = J + cg + c;
    float v = acc[c];
    if (jg >= k0 && jg < k0 + 64) v = DT[jg - k0][p];
    S[p][cg + c] = v;
  }
  __syncthreads();
  float* Rb = Rnew + (long)b * 65536 + J;
  for (int i = tid; i < 2048; i += 256) {
    int r = i >> 5, j4 = (i & 31) << 2;
    *(float4*)(Rb + (long)r * 1024 + j4) = *(float4*)&S[r][j4];
  }
  unsigned short* th = RTh + (long)b * 65536 + (long)J * 64;
  unsigned short* tl = RTl + (long)b * 65536 + (long)J * 64;
  for (int i = tid; i < 8192; i += 256) {
    int jl = i >> 6, pp = i & 63;
    float v = S[pp][jl];
    unsigned short h = bf16rne(v);
    float hf = __uint_as_float((unsigned)h << 16);
    th[i] = h;
    tl[i] = bf16rne(v - hf);
  }
}

// ---------------- GJ trailing update: 64x64 tiles, bf16x3 MFMA, batch-pinned ----------------
// grid (8 batches-x, 16 mtiles-y, 16 ntiles-z), 256 thr, LDS 32KB -> ~5 blk/CU.
__global__ __launch_bounds__(256) void gupd_k(const unsigned short* __restrict__ Ch, const unsigned short* __restrict__ Cl,
                                              const unsigned short* __restrict__ RTh, const unsigned short* __restrict__ RTl,
                                              const float* __restrict__ Rnew, float* __restrict__ W,
                                              unsigned short* __restrict__ ChN, unsigned short* __restrict__ ClN, int k0){
  __shared__ char lds[32768];   // 4 panels [64][128B], XOR-swizzled
  int b = blockIdx.x;
  const float* Rb = Rnew + (long)b * 65536;
  float* Wb = W + (long)b * 1048576;
  unsigned short* CnH = ChN + (long)b * 65536;
  unsigned short* CnL = ClN + (long)b * 65536;
  const int tid = threadIdx.x, l = tid & 63, wid = tid >> 6;
  const int wr = wid >> 1, wc = wid & 1;
  const int m0 = blockIdx.y * 64, n0 = blockIdx.z * 64;
  {
    const unsigned short* srcs[4] = {
      Ch  + (long)b * 65536 + (long)m0 * 64,
      Cl  + (long)b * 65536 + (long)m0 * 64,
      RTh + (long)b * 65536 + (long)n0 * 64,
      RTl + (long)b * 65536 + (long)n0 * 64 };
#pragma unroll
    for (int pnl = 0; pnl < 4; ++pnl) {
      const char* s = (const char*)srcs[pnl];
      char* d = lds + pnl * 8192;
      for (int i = tid; i < 512; i += 256) {
        int row = i >> 3, c16 = (i & 7) << 4;
        uint4 v = *(const uint4*)(s + row * 128 + c16);
        *(uint4*)(d + row * 128 + (c16 ^ ((row & 7) << 4))) = v;
      }
    }
  }
  __syncthreads();
  const int lrow = l & 15, kc16 = (l >> 4) << 4;
  f32x4 acc[2][2] = {};
#pragma unroll
  for (int kk = 0; kk < 2; ++kk) {      // two K=32 chunks (byte offset kk*64)
    bf16x8 ah[2], al4[2], bh[2], bl4[2];
#pragma unroll
    for (int t = 0; t < 2; ++t) {
      int ra = wr * 32 + t * 16 + lrow;
      int offa = (ra * 128 + kk * 64 + kc16) ^ ((ra & 7) << 4);
      ah[t]  = *(const bf16x8*)(lds + offa);
      al4[t] = *(const bf16x8*)(lds + 8192 + offa);
      int rb = wc * 32 + t * 16 + lrow;
      int offb = (rb * 128 + kk * 64 + kc16) ^ ((rb & 7) << 4);
      bh[t]  = *(const bf16x8*)(lds + 16384 + offb);
      bl4[t] = *(const bf16x8*)(lds + 24576 + offb);
    }
#pragma unroll
    for (int mi = 0; mi < 2; ++mi)
#pragma unroll
      for (int ni = 0; ni < 2; ++ni) {
        acc[mi][ni] = __builtin_amdgcn_mfma_f32_16x16x32_bf16(ah[mi],  bh[ni],  acc[mi][ni], 0, 0, 0);
        acc[mi][ni] = __builtin_amdgcn_mfma_f32_16x16x32_bf16(ah[mi],  bl4[ni], acc[mi][ni], 0, 0, 0);
        acc[mi][ni] = __builtin_amdgcn_mfma_f32_16x16x32_bf16(al4[mi], bh[ni],  acc[mi][ni], 0, 0, 0);
      }
  }
#pragma unroll
  for (int mi = 0; mi < 2; ++mi)
#pragma unroll
  for (int ni = 0; ni < 2; ++ni)
#pragma unroll
  for (int r = 0; r < 4; ++r) {
    int m = m0 + wr * 32 + mi * 16 + ((l >> 4) << 2) + r;
    int n = n0 + wc * 32 + ni * 16 + (l & 15);
    bool rowK = (m >= k0 && m < k0 + 64);
    bool colK = (n >= k0 && n < k0 + 64);
    float v;
    if (rowK)      v = Rb[(long)(m - k0) * 1024 + n];
    else if (colK) v = -acc[mi][ni][r];
    else           v = Wb[(long)m * 1024 + n] - acc[mi][ni][r];
    Wb[(long)m * 1024 + n] = v;
    int cn = n - k0 - 64;
    if (cn >= 0 && cn < 64) {
      unsigned short h = bf16rne(v);
      float hf = __uint_as_float((unsigned)h << 16);
      CnH[(long)m * 64 + cn] = h;
      CnL[(long)m * 64 + cn] = bf16rne(v - hf);
    }
  }
}

// ---------------- d0, diag, df col 0 ----------------
__global__ void ddiag_k(const float* __restrict__ W, const float* __restrict__ fi,
                        float* __restrict__ d0, float* __restrict__ diag, float* __restrict__ dfout){
  int t = blockIdx.x * 256 + threadIdx.x;
  int b = t >> 10, i = t & 1023;
  const float* Wb = W + (long)b * TT * TT;
  float dv = fi[t] * Wb[(long)i * TT];
  d0[t] = dv;
  diag[t] = Wb[(long)i * TT + i];
  dfout[(long)b * TT * 1025 + (long)i * 1025] = dv;
}

// ---------------- dx: compute, emit bf16 dx + bf16 dx^T + df store ----------------
__global__ __launch_bounds__(256) void dx_k(const float* __restrict__ A, const float* __restrict__ W,
                                            const float* __restrict__ diag, float* __restrict__ dfout,
                                            unsigned short* __restrict__ dxb, unsigned short* __restrict__ dxTb){
  int b = blockIdx.z;
  int i0 = blockIdx.y * 64, j0 = blockIdx.x * 64;
  const float* Wb = W + (long)b * TT * TT;
  const float* Ab = A + (long)b * TT * TT;
  __shared__ float Ls[64][65];
  __shared__ float Sx[64][65];
  int tid = threadIdx.x;
  for (int idx = tid; idx < 4096; idx += 256) {
    int r = idx >> 6, c = idx & 63;
    Ls[r][c] = Wb[(long)(j0 + r) * TT + i0 + c];
  }
  __syncthreads();
  for (int idx = tid; idx < 4096; idx += 256) {
    int r = idx >> 6, c = idx & 63;
    int i = i0 + r, j = j0 + c;
    float a = Ab[(long)i * TT + j];
    float v = 0.f;
    if (j > 0) v = a * diag[b * TT + j];
    if (i > 0) v -= a * Ls[c][r];
    dxb[(long)b * 1048576 + (long)i * 1024 + j] = bf16rne(v);
    Sx[r][c] = v;
  }
  __syncthreads();
  float* dfb = dfout + (long)b * TT * 1025;
  unsigned short* dtb = dxTb + (long)b * 1048576;
  for (int idx = tid; idx < 4096; idx += 256) {
    int r = idx >> 6, c = idx & 63;
    float v = Sx[c][r];
    dfb[(long)(j0 + r) * 1025 + i0 + 1 + c] = v;
    dtb[(long)(j0 + r) * 1024 + i0 + c] = bf16rne(v);
  }
}

extern "C" void kernel_launch(void* const* d_in, const int* in_sizes, int n_in,
                              void* d_out, int out_size, void* d_ws, size_t ws_size,
                              hipStream_t stream){
  const float* input   = (const float*)d_in[0];
  const float* Wtp     = (const float*)d_in[1];
  const float* btp     = (const float*)d_in[2];
  const float* Wtc     = (const float*)d_in[3];
  const float* btc     = (const float*)d_in[4];
  const float* wfi     = (const float*)d_in[5];
  const float* Wbil    = (const float*)d_in[6];
  const float* exparam = (const float*)d_in[7];
  const float* Wfz     = (const float*)d_in[8];
  const float* bfz     = (const float*)d_in[9];

  if (ws_size < 150000000UL) return;

  float* ws   = (float*)d_ws;
  float* sem   = ws;                    // 4,194,304 f
  float* strv  = ws + 4194304;          // 4,194,304 f  [later: dxb bf16]
  float* Abuf  = ws + 8388608;          // 8,388,608 f  [later: finpb bf16]
  float* Wbuf  = ws + 16777216;         // 8,388,608 f
  unsigned short* strb = (unsigned short*)(ws + 25165824);
  unsigned short* tpb  = (unsigned short*)(ws + 27262976);
  unsigned short* tcb  = (unsigned short*)(ws + 29360128);
  unsigned short* tpwb = (unsigned short*)(ws + 31457280);
  unsigned short* wtpb = (unsigned short*)(ws + 33554432);
  unsigned short* wtcb = (unsigned short*)(ws + 33685504);
  unsigned short* wbilT= (unsigned short*)(ws + 33816576);
  unsigned short* wfzb = (unsigned short*)(ws + 33947648);
  float* fi    = ws + 34340864;         // 8192
  float* csp   = ws + 34349056;         // 65,536
  float* d0    = ws + 34414592;         // 8192
  float* dg    = ws + 34422784;         // 8192
  float* Dinv  = ws + 34430976;         // 32,768
  float* Rnew  = ws + 34463744;         // 524,288
  unsigned short* ChA = (unsigned short*)(ws + 34988032);  // 8x1024x64 bf16
  unsigned short* ClA = (unsigned short*)(ws + 35250176);
  unsigned short* ChB = (unsigned short*)(ws + 35512320);
  unsigned short* ClB = (unsigned short*)(ws + 35774464);
  unsigned short* RTh = (unsigned short*)(ws + 36036608);
  unsigned short* RTl = (unsigned short*)(ws + 36298752);
  unsigned short* dxb   = (unsigned short*)strv;
  unsigned short* dxTb  = (unsigned short*)(ws + 25165824);
  unsigned short* semTb = (unsigned short*)(ws + 29360128);
  unsigned short* finpb = (unsigned short*)Abuf;

  float* outp = (float*)d_out;
  float* dfp  = outp + 4194304;

  split_k<<<8192, 256, 0, stream>>>(input, sem, strv);
  castrow_k<<<4096, 256, 0, stream>>>(strv, strb);
  castrow_k<<<256, 256, 0, stream>>>(Wtp, wtpb);
  castrow_k<<<256, 256, 0, stream>>>(Wtc, wtcb);
  castrow_k<<<768, 256, 0, stream>>>(Wfz, wfzb);
  castT_k<<<dim3(16,16,1), 256, 0, stream>>>(Wbil, wbilT, 512, 512, 0, 0);
  fi_k<<<2048, 256, 0, stream>>>(strv, wfi, fi);
  mgemm_k<1,1><<<dim3(4,64,1),256,0,stream>>>(strb, wtpb, tpb, 512, 512, 512, 512, 0,0,0, btp, nullptr,0,nullptr);
  mgemm_k<1,1><<<dim3(4,64,1),256,0,stream>>>(strb, wtcb, tcb, 512, 512, 512, 512, 0,0,0, btc, nullptr,0,nullptr);
  mgemm_k<0,1><<<dim3(4,64,1),256,0,stream>>>(tpb, wbilT, tpwb, 512, 512, 512, 512, 0,0,0, nullptr, nullptr,0,nullptr);
  mgemm_k<2,0><<<dim3(8,8,8),256,0,stream>>>(tpwb, tcb, Abuf, 512, 512, 512, 1024, 524288,524288,1048576, nullptr, nullptr,0,nullptr);
  castT_k<<<dim3(16,32,8), 256, 0, stream>>>(sem, semTb, 1024, 512, 524288, 524288);
  colsum_k<<<dim3(4,8,8),256,0,stream>>>(Abuf, csp);
  buildw_k<<<32768,256,0,stream>>>(Abuf, fi, csp, Wbuf, ChA, ClA);
  // blocked in-place Gauss-Jordan: {dinv, prep, gupd} x 16, batch-pinned to XCDs
  for (int s = 0; s < 16; ++s) {
    int k0 = s * NB;
    unsigned short* ChI = (s & 1) ? ChB : ChA;
    unsigned short* ClI = (s & 1) ? ClB : ClA;
    unsigned short* ChO = (s & 1) ? ChA : ChB;
    unsigned short* ClO = (s & 1) ? ClA : ClB;
    gj_dinv_k<<<8,256,0,stream>>>(Wbuf, Dinv, k0);
    gj_prep_k<<<dim3(8,8),256,0,stream>>>(Wbuf, Dinv, Rnew, RTh, RTl, k0);
    gupd_k<<<dim3(8,16,16),256,0,stream>>>(ChI, ClI, RTh, RTl, Rnew, Wbuf, ChO, ClO, k0);
  }
  ddiag_k<<<32,256,0,stream>>>(Wbuf, fi, d0, dg, dfp);
  dx_k<<<dim3(16,16,8),256,0,stream>>>(Abuf, Wbuf, dg, dfp, dxb, dxTb);
  semcopy_k<<<4096,256,0,stream>>>(sem, finpb);
  mgemm_k<4,1><<<dim3(4,8,8),256,0,stream>>>(dxTb, semTb, finpb + 512, 1024, 1024, 1024, 1536,
                                             1048576, 524288, 1572864, nullptr, d0, 1024, exparam);
  mgemm_k<0,1><<<dim3(4,8,8),256,0,stream>>>(dxb, semTb, finpb + 1024, 1024, 1024, 1024, 1536,
                                             1048576, 524288, 1572864, nullptr, nullptr,0,nullptr);
  mgemm_k<3,0><<<dim3(4,64,1),256,0,stream>>>(finpb, wfzb, outp, 1536, 1536, 1536, 512, 0,0,0, bfz, nullptr,0,nullptr);
}